// Round 5
// baseline (401.138 us; speedup 1.0000x reference)
//
#include <hip/hip_runtime.h>

typedef _Float16 f16;
typedef f16  f16x8 __attribute__((ext_vector_type(8)));
typedef f16  f16x4 __attribute__((ext_vector_type(4)));
typedef float f32x4 __attribute__((ext_vector_type(4)));
typedef unsigned int u32;

// ---- d_ws layout (f16 elems): hi/lo split weights, 352,256 B ----
#define W1T_HI 0        // [4][128][32]  W1T[e][u][f]
#define W1T_LO 16384
#define V1T_HI 32768    // [128][32]
#define V1T_LO 36864
#define W2T_HI 40960    // [4][64][160]  W2T[e][u][k], k = [h1(128), node(32)]
#define W2T_LO 81920
#define V2T_HI 122880   // [64][32]
#define V2T_LO 124928
#define WIT_HI 126976   // [128][96]     WiT[ua][k], k = [h2(64), node(32)]
#define WIT_LO 139264
#define WJT_HI 151552
#define WJT_LO 163840
#define WS_SRC 88064

// ---- dynamic LDS (bytes): 81,920 B = 80 KB -> 2 blocks/CU ----
// 8-wave layout. Per-wave private PT rows: waves 0..3 in PTB (8 KB),
// waves 4..7 in the first 8 KB of ANNB_HI (dead during PT liveness).
// PT_LO = full ANNB_LO (8 KB, 1 KB/wave). f32 merge scratch overlays
// ANNB_HI.. between barriers.
#define ADJB_HI 0        // f16 [4][64][64], XOR swizzle (unit8 ^ (m&7))      32768 B
#define ADJB_LO 32768    // u8  [4][64][64], same swizzle, straight bytes    16384 B
#define ANNB_HI 49152    // f16 [64][128]: h1 (h2 overlays cols 64..127)      16384 B
#define ANNB_LO 65536    // u8  [64][128]; doubles as PT_LO plane              8192 B
#define PTB     73728    // per-wave transposed P/Q (waves 0..3); node overlay 8192 B
#define LDS_BYTES 81920

__device__ __forceinline__ f32x4 mfma16(f16x8 a, f16x8 b, f32x4 c){
  return __builtin_amdgcn_mfma_f32_16x16x32_f16(a, b, c, 0, 0, 0);
}
// rcp-based activations: exact at +-inf (rcp(inf)=0), no clamp needed, ~6 VALU ops.
__device__ __forceinline__ float fast_tanh(float x){
  float e = __expf(2.f * x);
  return 1.f - 2.f * __builtin_amdgcn_rcpf(e + 1.f);
}
__device__ __forceinline__ float fast_sigmoid(float x){
  return __builtin_amdgcn_rcpf(1.f + __expf(-x));
}

// ---- 8-bit lo-plane codec: byte = top 8 bits of f16(lo), RTN via +0x80.
// Decode = byte into HIGH byte of f16 lane -> 4x v_perm_b32 per 8 elems.
__device__ __forceinline__ unsigned char enc1(float lo){
  f16 h = (f16)lo;
  unsigned short u = __builtin_bit_cast(unsigned short, h);
  return (unsigned char)(((u32)u + 0x80u) >> 8);
}
__device__ __forceinline__ void enc8(unsigned char* p, const float* lo){
  u32 a = 0, b = 0;
  #pragma unroll
  for (int j = 0; j < 4; ++j) a |= (u32)enc1(lo[j]) << (8*j);
  #pragma unroll
  for (int j = 0; j < 4; ++j) b |= (u32)enc1(lo[4+j]) << (8*j);
  uint2 v = {a, b};
  *(uint2*)p = v;
}
__device__ __forceinline__ u32 enc4(const float* lo){
  return (u32)enc1(lo[0]) | ((u32)enc1(lo[1]) << 8)
       | ((u32)enc1(lo[2]) << 16) | ((u32)enc1(lo[3]) << 24);
}
__device__ __forceinline__ f16x8 dec8(const unsigned char* p){
  uint2 d = *(const uint2*)p;
  u32 w[4];
  w[0] = __builtin_amdgcn_perm(0u, d.x, 0x010c000cu);  // [0]=0,[1]=b0,[2]=0,[3]=b1
  w[1] = __builtin_amdgcn_perm(0u, d.x, 0x030c020cu);  // b2, b3
  w[2] = __builtin_amdgcn_perm(0u, d.y, 0x010c000cu);  // b4, b5
  w[3] = __builtin_amdgcn_perm(0u, d.y, 0x030c020cu);  // b6, b7
  f16x8 r; __builtin_memcpy(&r, w, 16);
  return r;
}

__global__ void prep_weights(const float* __restrict__ W1, const float* __restrict__ V1,
                             const float* __restrict__ W2, const float* __restrict__ V2,
                             const float* __restrict__ Wi, const float* __restrict__ Wj,
                             f16* __restrict__ ws){
  int i = blockIdx.x * 256 + threadIdx.x;
  if (i >= WS_SRC) return;
  float v; int hi_off, lo_off, idx;
  int j = i;
  if (j < 16384){ int e = j >> 12, u = (j >> 5) & 127, f = j & 31;
    v = W1[(e*32 + f)*128 + u]; hi_off = W1T_HI; lo_off = W1T_LO; idx = j; }
  else if ((j -= 16384) < 4096){ int u = j >> 5, f = j & 31;
    v = V1[f*128 + u]; hi_off = V1T_HI; lo_off = V1T_LO; idx = j; }
  else if ((j -= 4096) < 40960){ int e = j / 10240, r = j % 10240, u = r / 160, k = r % 160;
    v = W2[e*10240 + k*64 + u]; hi_off = W2T_HI; lo_off = W2T_LO; idx = j; }
  else if ((j -= 40960) < 2048){ int u = j >> 5, f = j & 31;
    v = V2[f*64 + u]; hi_off = V2T_HI; lo_off = V2T_LO; idx = j; }
  else if ((j -= 2048) < 12288){ int ua = j / 96, k = j % 96;
    v = Wi[k*128 + ua]; hi_off = WIT_HI; lo_off = WIT_LO; idx = j; }
  else { j -= 12288; int ua = j / 96, k = j % 96;
    v = Wj[k*128 + ua]; hi_off = WJT_HI; lo_off = WJT_LO; idx = j; }
  f16 h = (f16)v;
  ws[hi_off + idx] = h;
  ws[lo_off + idx] = (f16)(v - (float)h);
}

// one block = one batch; 8 waves; edge-type split: waves 0..3 (eg=0) own
// e in {0,1}, waves 4..7 (eg=1) own e in {2,3}. 80 KB LDS -> 2 blocks/CU,
// 16 waves/CU.
// __launch_bounds__ 2nd arg is MIN BLOCKS PER CU (CUDA semantics): rounds
// 2-4 used 4 -> 32 waves/CU -> 64-VGPR cap -> persistent spill (scratch
// FETCH+WRITE traffic). LDS already caps residency at 2 blocks/CU, so
// request exactly 2 -> 128-VGPR budget, zero spill, same occupancy.
__global__ __launch_bounds__(512, 2) void encoder_main(
    const float* __restrict__ adj, const float* __restrict__ node,
    const float* __restrict__ b1, const float* __restrict__ c1,
    const float* __restrict__ b2, const float* __restrict__ c2,
    const float* __restrict__ bi, const float* __restrict__ bj,
    const f16* __restrict__ wb, float* __restrict__ out)
{
  extern __shared__ unsigned char ldsb[];
  f16* adjh            = (f16*)(ldsb + ADJB_HI);
  unsigned char* adjl  = ldsb + ADJB_LO;
  f16* annh            = (f16*)(ldsb + ANNB_HI);
  unsigned char* annl  = ldsb + ANNB_LO;
  float* scr           = (float*)(ldsb + ANNB_HI);   // f32 merge scratch overlay
  f16* nodeH           = (f16*)(ldsb + PTB);          // staging overlay
  f16* nodeLo          = (f16*)(ldsb + PTB + 4096);   // staging overlay

  const int tid  = threadIdx.x;
  const int w    = tid >> 6;          // 0..7
  const int lane = tid & 63;
  const int q    = lane >> 4;
  const int l15  = lane & 15;
  const int eg   = w >> 2;            // edge group: e in {eg*2, eg*2+1}
  const int w4   = w & 3;             // u-slice index within group
  const int b    = blockIdx.x;
  const f32x4 z4 = {0.f, 0.f, 0.f, 0.f};

  // per-wave private transpose rows: 16 rows x 128 B hi + 16 rows x 64 B lo
  unsigned char* ptb = ldsb + ((w < 4) ? (PTB + w*2048) : (ANNB_HI + (w - 4)*2048));
  unsigned char* ptl = ldsb + ANNB_LO + w*1024;
  const int ptrow  = l15 * 128;
  const int ptlrow = l15 * 64;

  // ---------------- stage: adjacency + node -> split LDS ----------------
  {
    const float* ap = adj + (size_t)b * 20480;
    #pragma unroll
    for (int i = 0; i < 4; ++i){
      int fu = tid + 512*i;                       // fu = (e*64 + m)*8 + uc
      int e = fu >> 9, m = (fu >> 3) & 63, uc = fu & 7;
      const float* p = ap + (m*64 + uc*8)*5 + e + 1;    // skip edge type 0
      float v[8], lo[8]; f16x8 hi;
      #pragma unroll
      for (int jj = 0; jj < 8; ++jj) v[jj] = p[jj*5];
      #pragma unroll
      for (int jj = 0; jj < 8; ++jj){
        f16 h = (f16)v[jj]; hi[jj] = h; lo[jj] = v[jj] - (float)h;
      }
      int off = e*4096 + m*64 + ((uc ^ (m & 7)) * 8);
      *(f16x8*)&adjh[off] = hi;
      enc8(&adjl[off], lo);
    }
    if (tid < 256){
      const float* np = node + (size_t)b * 2048 + (tid & 63)*32 + (tid >> 6)*8;
      float4 a = *(const float4*)np, c = *(const float4*)(np + 4);
      float v[8] = {a.x, a.y, a.z, a.w, c.x, c.y, c.z, c.w};
      f16x8 hi, lo;
      #pragma unroll
      for (int jj = 0; jj < 8; ++jj){
        f16 h = (f16)v[jj]; hi[jj] = h; lo[jj] = (f16)(v[jj] - (float)h);
      }
      int n = tid & 63, un = tid >> 6;
      *(f16x8*)&nodeH [n*32 + ((un ^ (n & 3)) * 8)] = hi;
      *(f16x8*)&nodeLo[n*32 + ((un ^ (n & 3)) * 8)] = lo;
    }
  }
  __syncthreads();

  // node A-frags hi+lo (registers; node LDS region dead after this + barrier)
  f16x8 anh[4], anl[4];
  #pragma unroll
  for (int mt = 0; mt < 4; ++mt){
    anh[mt] = *(const f16x8*)&nodeH [(mt*16 + l15)*32 + ((q ^ (l15 & 3)) * 8)];
    anl[mt] = *(const f16x8*)&nodeLo[(mt*16 + l15)*32 + ((q ^ (l15 & 3)) * 8)];
  }
  __syncthreads();                                // protect PT/node overlay

  // ============ layer 1: h1 = tanh(sum_e A_e(node@W1+b1) + node@V1 + c1) ============
  f32x4 acc1[4][2];
  #pragma unroll
  for (int mt = 0; mt < 4; ++mt){ acc1[mt][0] = z4; acc1[mt][1] = z4; }

  #pragma unroll
  for (int i = 0; i < 2; ++i){
    const int e = eg*2 + i;
    #pragma unroll
    for (int ut = 0; ut < 2; ++ut){
      const int u = w4*32 + ut*16 + l15;
      f16x8 wh = *(const f16x8*)&wb[W1T_HI + (e*128 + u)*32 + q*8];
      f16x8 wl = *(const f16x8*)&wb[W1T_LO + (e*128 + u)*32 + q*8];
      float bias = b1[e*128 + u];
      #pragma unroll
      for (int mt = 0; mt < 4; ++mt){
        f32x4 pf = mfma16(anh[mt], wh, z4);
        pf = mfma16(anl[mt], wh, pf);
        pf = mfma16(anh[mt], wl, pf);
        f16x4 ph; float lo4[4];
        #pragma unroll
        for (int r = 0; r < 4; ++r){
          float v = pf[r] + bias;
          f16 h = (f16)v; ph[r] = h; lo4[r] = v - (float)h;
        }
        int unit = ((mt*2 + (q >> 1)) ^ (l15 & 7));      // n0 = mt*16+q*4
        *(f16x4*)(ptb + ptrow + unit*16 + (q & 1)*8) = ph;       // PT_HI[u_loc][n]
        *(u32*)(ptl + ptlrow + unit*8 + (q & 1)*4) = enc4(lo4);  // PT_LO
      }
      // adjacency fragments streamed per-(ks,mt): 8 regs transient, not 64.
      #pragma unroll
      for (int ks = 0; ks < 2; ++ks){
        int pu = ((ks*4 + q) ^ (l15 & 7));
        f16x8 bph = *(const f16x8*)(ptb + ptrow + pu*16);
        f16x8 bpl = dec8(ptl + ptlrow + pu*8);
        #pragma unroll
        for (int mt = 0; mt < 4; ++mt){
          int off = e*4096 + (mt*16 + l15)*64 + (((ks*4 + q) ^ (l15 & 7)) * 8);
          f16x8 ah = *(const f16x8*)&adjh[off];
          f16x8 al = dec8(&adjl[off]);
          acc1[mt][ut] = mfma16(ah, bph, acc1[mt][ut]);
          acc1[mt][ut] = mfma16(al, bph, acc1[mt][ut]);
          acc1[mt][ut] = mfma16(ah, bpl, acc1[mt][ut]);
        }
      }
    }
  }
  __syncthreads();   // B0: all PT/PT_LO reads done before scratch overlays them

  // merge: eg0 folds V1 term; eg1 publishes partials to f32 scratch.
  // scratch swizzle: u' = u ^ ((n&4)<<2) -> max 2-way bank alias (free).
  if (eg == 0){
    #pragma unroll
    for (int ut = 0; ut < 2; ++ut){
      const int u = w4*32 + ut*16 + l15;
      f16x8 wh = *(const f16x8*)&wb[V1T_HI + u*32 + q*8];
      f16x8 wl = *(const f16x8*)&wb[V1T_LO + u*32 + q*8];
      #pragma unroll
      for (int mt = 0; mt < 4; ++mt){
        acc1[mt][ut] = mfma16(anh[mt], wh, acc1[mt][ut]);
        acc1[mt][ut] = mfma16(anl[mt], wh, acc1[mt][ut]);
        acc1[mt][ut] = mfma16(anh[mt], wl, acc1[mt][ut]);
      }
    }
  } else {
    #pragma unroll
    for (int mt = 0; mt < 4; ++mt)
      #pragma unroll
      for (int ut = 0; ut < 2; ++ut)
        #pragma unroll
        for (int r = 0; r < 4; ++r){
          int n = mt*16 + q*4 + r;
          int u = w4*32 + ut*16 + l15;
          scr[n*128 + (u ^ ((n & 4) << 2))] = acc1[mt][ut][r];
        }
  }
  __syncthreads();   // B1: scratch ready
  if (eg == 0){
    #pragma unroll
    for (int mt = 0; mt < 4; ++mt)
      #pragma unroll
      for (int ut = 0; ut < 2; ++ut)
        #pragma unroll
        for (int r = 0; r < 4; ++r){
          int n = mt*16 + q*4 + r;
          int u = w4*32 + ut*16 + l15;
          acc1[mt][ut][r] += scr[n*128 + (u ^ ((n & 4) << 2))];
        }
  }
  __syncthreads();   // B2: scratch reads done before ann writes overlay it
  if (eg == 0){
    #pragma unroll
    for (int ut = 0; ut < 2; ++ut){
      const int u = w4*32 + ut*16 + l15;
      float cv = c1[u];
      #pragma unroll
      for (int mt = 0; mt < 4; ++mt)
        #pragma unroll
        for (int r = 0; r < 4; ++r){
          float h = fast_tanh(acc1[mt][ut][r] + cv);
          f16 hh = (f16)h;
          int row = mt*16 + q*4 + r;
          int unit = ((u >> 3) ^ (row & 7));
          annh[row*128 + unit*8 + (u & 7)] = hh;                   // h1 cols 0..127
          annl[row*128 + unit*8 + (u & 7)] = enc1(h - (float)hh);
        }
    }
  }
  __syncthreads();   // B3: h1 ready

  // ============ layer 2: h2 = tanh(sum_e A_e(ann@W2+b2) + node@V2 + c2) ============
  const int u2 = w4*16 + l15;
  f32x4 qf[2][4];                                 // [i][mt], group's 2 edge types
  #pragma unroll
  for (int mt = 0; mt < 4; ++mt){
    #pragma unroll
    for (int i = 0; i < 2; ++i){
      const int e = eg*2 + i;
      const f16* w2h = &wb[W2T_HI + (e*64 + u2)*160];
      const f16* w2l = &wb[W2T_LO + (e*64 + u2)*160];
      f16x8 wnh = *(const f16x8*)&w2h[4*32 + q*8];
      f16x8 wnl = *(const f16x8*)&w2l[4*32 + q*8];
      f32x4 t = mfma16(anh[mt], wnh, z4);          // node part k=128..159
      t = mfma16(anl[mt], wnh, t);
      t = mfma16(anh[mt], wnl, t);
      // ann fragments streamed per-(i,ks): 8 regs transient, not 64.
      #pragma unroll
      for (int ks = 0; ks < 4; ++ks){
        int off = (mt*16 + l15)*128 + (((ks*4 + q) ^ (l15 & 7)) * 8);
        f16x8 axh = *(const f16x8*)&annh[off];
        f16x8 axl = dec8(&annl[off]);
        f16x8 wh = *(const f16x8*)&w2h[ks*32 + q*8];
        f16x8 wl = *(const f16x8*)&w2l[ks*32 + q*8];
        t = mfma16(axh, wh, t);
        t = mfma16(axl, wh, t);
        t = mfma16(axh, wl, t);
      }
      qf[i][mt] = t;
    }
  }
  __syncthreads();   // B4: ann reads done before QT overlays annl / annh(eg1)

  f32x4 acc2[4];
  #pragma unroll
  for (int mt = 0; mt < 4; ++mt) acc2[mt] = z4;
  #pragma unroll
  for (int i = 0; i < 2; ++i){
    const int e = eg*2 + i;
    float bias = b2[e*64 + u2];
    #pragma unroll
    for (int mt = 0; mt < 4; ++mt){
      f16x4 ph; float lo4[4];
      #pragma unroll
      for (int r = 0; r < 4; ++r){
        float v = qf[i][mt][r] + bias;
        f16 h = (f16)v; ph[r] = h; lo4[r] = v - (float)h;
      }
      int unit = ((mt*2 + (q >> 1)) ^ (l15 & 7));
      *(f16x4*)(ptb + ptrow + unit*16 + (q & 1)*8) = ph;       // QT_HI[u_loc][n]
      *(u32*)(ptl + ptlrow + unit*8 + (q & 1)*4) = enc4(lo4);  // QT_LO
    }
    #pragma unroll
    for (int ks = 0; ks < 2; ++ks){
      int pu = ((ks*4 + q) ^ (l15 & 7));
      f16x8 bph = *(const f16x8*)(ptb + ptrow + pu*16);
      f16x8 bpl = dec8(ptl + ptlrow + pu*8);
      #pragma unroll
      for (int mt = 0; mt < 4; ++mt){
        int off = e*4096 + (mt*16 + l15)*64 + (((ks*4 + q) ^ (l15 & 7)) * 8);
        f16x8 ah = *(const f16x8*)&adjh[off];
        f16x8 al = dec8(&adjl[off]);
        acc2[mt] = mfma16(ah, bph, acc2[mt]);
        acc2[mt] = mfma16(al, bph, acc2[mt]);
        acc2[mt] = mfma16(ah, bpl, acc2[mt]);
      }
    }
  }
  // B4b: scr2 (16 KB @ ANNB_HI) overlays waves 4..7's QT_HI buffers — must
  // wait until ALL eg1 waves finish their QT reads, not just the writer.
  __syncthreads();
  if (eg == 0){
    f16x8 wh = *(const f16x8*)&wb[V2T_HI + u2*32 + q*8];
    f16x8 wl = *(const f16x8*)&wb[V2T_LO + u2*32 + q*8];
    #pragma unroll
    for (int mt = 0; mt < 4; ++mt){
      acc2[mt] = mfma16(anh[mt], wh, acc2[mt]);
      acc2[mt] = mfma16(anl[mt], wh, acc2[mt]);
      acc2[mt] = mfma16(anh[mt], wl, acc2[mt]);
    }
  } else {
    #pragma unroll
    for (int mt = 0; mt < 4; ++mt)
      #pragma unroll
      for (int r = 0; r < 4; ++r){
        int n = mt*16 + q*4 + r;
        scr[n*64 + (u2 ^ ((n & 4) << 2))] = acc2[mt][r];
      }
  }
  __syncthreads();   // B5: scratch2 ready
  if (eg == 0){
    #pragma unroll
    for (int mt = 0; mt < 4; ++mt)
      #pragma unroll
      for (int r = 0; r < 4; ++r){
        int n = mt*16 + q*4 + r;
        acc2[mt][r] += scr[n*64 + (u2 ^ ((n & 4) << 2))];
      }
  }
  __syncthreads();   // B6: scratch2 reads done before h2 writes overlay it
  if (eg == 0){
    float cv = c2[u2];
    const int uc = 64 + u2;
    #pragma unroll
    for (int mt = 0; mt < 4; ++mt)
      #pragma unroll
      for (int r = 0; r < 4; ++r){
        float h = fast_tanh(acc2[mt][r] + cv);
        f16 hh = (f16)h;
        int row = mt*16 + q*4 + r;
        int unit = ((uc >> 3) ^ (row & 7));
        annh[row*128 + unit*8 + (uc & 7)] = hh;                  // h2 cols 64..127
        annl[row*128 + unit*8 + (uc & 7)] = enc1(h - (float)hh);
      }
  }
  __syncthreads();   // B7: h2 ready

  // ============ aggregation: out = tanh(sum_n sigmoid(.)·tanh(.)) ============
  const int ua = w*16 + l15;                      // 8 waves x 16 = 128
  f16x8 wih[3], wil[3], wjh[3], wjl[3];
  #pragma unroll
  for (int ks = 0; ks < 3; ++ks){
    wih[ks] = *(const f16x8*)&wb[WIT_HI + ua*96 + ks*32 + q*8];
    wil[ks] = *(const f16x8*)&wb[WIT_LO + ua*96 + ks*32 + q*8];
    wjh[ks] = *(const f16x8*)&wb[WJT_HI + ua*96 + ks*32 + q*8];
    wjl[ks] = *(const f16x8*)&wb[WJT_LO + ua*96 + ks*32 + q*8];
  }
  float bib = bi[ua], bjb = bj[ua];
  float s = 0.f;
  #pragma unroll
  for (int mt = 0; mt < 4; ++mt){
    f16x8 gh[2], gl[2];
    #pragma unroll
    for (int ks = 0; ks < 2; ++ks){
      int off = (mt*16 + l15)*128 + (((8 + ks*4 + q) ^ (l15 & 7)) * 8);
      gh[ks] = *(const f16x8*)&annh[off];
      gl[ks] = dec8(&annl[off]);
    }
    f32x4 ia = mfma16(anh[mt], wih[2], z4);       // node part k=64..95
    ia = mfma16(anl[mt], wih[2], ia);
    ia = mfma16(anh[mt], wil[2], ia);
    f32x4 ja = mfma16(anh[mt], wjh[2], z4);
    ja = mfma16(anl[mt], wjh[2], ja);
    ja = mfma16(anh[mt], wjl[2], ja);
    #pragma unroll
    for (int ks = 0; ks < 2; ++ks){
      ia = mfma16(gh[ks], wih[ks], ia);
      ia = mfma16(gl[ks], wih[ks], ia);
      ia = mfma16(gh[ks], wil[ks], ia);
      ja = mfma16(gh[ks], wjh[ks], ja);
      ja = mfma16(gl[ks], wjh[ks], ja);
      ja = mfma16(gh[ks], wjl[ks], ja);
    }
    #pragma unroll
    for (int r = 0; r < 4; ++r)
      s += fast_sigmoid(ia[r] + bib) * fast_tanh(ja[r] + bjb);
  }
  s += __shfl_xor(s, 16);
  s += __shfl_xor(s, 32);
  if (q == 0) out[(size_t)b*128 + ua] = fast_tanh(s);
}

extern "C" void kernel_launch(void* const* d_in, const int* in_sizes, int n_in,
                              void* d_out, int out_size, void* d_ws, size_t ws_size,
                              hipStream_t stream) {
  (void)in_sizes; (void)n_in; (void)out_size; (void)ws_size;
  const float* adj  = (const float*)d_in[0];
  // d_in[1] = hidden (zeros, rank-2): unused by the reference path
  const float* node = (const float*)d_in[2];
  const float* W1   = (const float*)d_in[3];
  const float* b1   = (const float*)d_in[4];
  const float* V1   = (const float*)d_in[5];
  const float* c1   = (const float*)d_in[6];
  const float* W2   = (const float*)d_in[7];
  const float* b2   = (const float*)d_in[8];
  const float* V2   = (const float*)d_in[9];
  const float* c2   = (const float*)d_in[10];
  const float* Wi   = (const float*)d_in[11];
  const float* bi   = (const float*)d_in[12];
  const float* Wj   = (const float*)d_in[13];
  const float* bj   = (const float*)d_in[14];
  f16* wb    = (f16*)d_ws;
  float* out = (float*)d_out;

  hipFuncSetAttribute((const void*)encoder_main,
                      hipFuncAttributeMaxDynamicSharedMemorySize, LDS_BYTES);

  prep_weights<<<(WS_SRC + 255) / 256, 256, 0, stream>>>(W1, V1, W2, V2, Wi, Wj, wb);
  encoder_main<<<2048, 512, LDS_BYTES, stream>>>(adj, node, b1, c1, b2, c2, bi, bj, wb, out);
}

// Round 6
// 388.420 us; speedup vs baseline: 1.0327x; 1.0327x over previous
//
#include <hip/hip_runtime.h>

typedef _Float16 f16;
typedef f16  f16x8 __attribute__((ext_vector_type(8)));
typedef f16  f16x4 __attribute__((ext_vector_type(4)));
typedef float f32x4 __attribute__((ext_vector_type(4)));
typedef unsigned int u32;

// ---- d_ws layout (f16 elems): hi/lo split weights, 352,256 B ----
#define W1T_HI 0        // [4][128][32]  W1T[e][u][f]
#define W1T_LO 16384
#define V1T_HI 32768    // [128][32]
#define V1T_LO 36864
#define W2T_HI 40960    // [4][64][160]  W2T[e][u][k], k = [h1(128), node(32)]
#define W2T_LO 81920
#define V2T_HI 122880   // [64][32]
#define V2T_LO 124928
#define WIT_HI 126976   // [128][96]     WiT[ua][k], k = [h2(64), node(32)]
#define WIT_LO 139264
#define WJT_HI 151552
#define WJT_LO 163840
#define WS_SRC 88064

// ---- dynamic LDS (bytes): 81,920 B = 80 KB -> 2 blocks/CU ----
// 8-wave layout. Per-wave private PT rows: waves 0..3 in PTB (8 KB),
// waves 4..7 in the first 8 KB of ANNB_HI (dead during PT liveness).
// PT_LO = full ANNB_LO (8 KB, 1 KB/wave). f32 merge scratch overlays
// ANNB_HI.. between barriers.
#define ADJB_HI 0        // f16 [4][64][64], XOR swizzle (unit8 ^ (m&7))      32768 B
#define ADJB_LO 32768    // u8  [4][64][64], same swizzle, straight bytes    16384 B
#define ANNB_HI 49152    // f16 [64][128]: h1 (h2 overlays cols 64..127)      16384 B
#define ANNB_LO 65536    // u8  [64][128]; doubles as PT_LO plane              8192 B
#define PTB     73728    // per-wave transposed P/Q (waves 0..3); node overlay 8192 B
#define LDS_BYTES 81920

__device__ __forceinline__ f32x4 mfma16(f16x8 a, f16x8 b, f32x4 c){
  return __builtin_amdgcn_mfma_f32_16x16x32_f16(a, b, c, 0, 0, 0);
}
// rcp-based activations: exact at +-inf (rcp(inf)=0), no clamp needed, ~6 VALU ops.
__device__ __forceinline__ float fast_tanh(float x){
  float e = __expf(2.f * x);
  return 1.f - 2.f * __builtin_amdgcn_rcpf(e + 1.f);
}
__device__ __forceinline__ float fast_sigmoid(float x){
  return __builtin_amdgcn_rcpf(1.f + __expf(-x));
}

// ---- 8-bit lo-plane codec: byte = top 8 bits of f16(lo), RTN via +0x80.
// Decode = byte into HIGH byte of f16 lane -> 4x v_perm_b32 per 8 elems.
__device__ __forceinline__ unsigned char enc1(float lo){
  f16 h = (f16)lo;
  unsigned short u = __builtin_bit_cast(unsigned short, h);
  return (unsigned char)(((u32)u + 0x80u) >> 8);
}
__device__ __forceinline__ void enc8(unsigned char* p, const float* lo){
  u32 a = 0, b = 0;
  #pragma unroll
  for (int j = 0; j < 4; ++j) a |= (u32)enc1(lo[j]) << (8*j);
  #pragma unroll
  for (int j = 0; j < 4; ++j) b |= (u32)enc1(lo[4+j]) << (8*j);
  uint2 v = {a, b};
  *(uint2*)p = v;
}
__device__ __forceinline__ u32 enc4(const float* lo){
  return (u32)enc1(lo[0]) | ((u32)enc1(lo[1]) << 8)
       | ((u32)enc1(lo[2]) << 16) | ((u32)enc1(lo[3]) << 24);
}
__device__ __forceinline__ f16x8 dec8(const unsigned char* p){
  uint2 d = *(const uint2*)p;
  u32 w[4];
  w[0] = __builtin_amdgcn_perm(0u, d.x, 0x010c000cu);  // [0]=0,[1]=b0,[2]=0,[3]=b1
  w[1] = __builtin_amdgcn_perm(0u, d.x, 0x030c020cu);  // b2, b3
  w[2] = __builtin_amdgcn_perm(0u, d.y, 0x010c000cu);  // b4, b5
  w[3] = __builtin_amdgcn_perm(0u, d.y, 0x030c020cu);  // b6, b7
  f16x8 r; __builtin_memcpy(&r, w, 16);
  return r;
}

__global__ void prep_weights(const float* __restrict__ W1, const float* __restrict__ V1,
                             const float* __restrict__ W2, const float* __restrict__ V2,
                             const float* __restrict__ Wi, const float* __restrict__ Wj,
                             f16* __restrict__ ws){
  int i = blockIdx.x * 256 + threadIdx.x;
  if (i >= WS_SRC) return;
  float v; int hi_off, lo_off, idx;
  int j = i;
  if (j < 16384){ int e = j >> 12, u = (j >> 5) & 127, f = j & 31;
    v = W1[(e*32 + f)*128 + u]; hi_off = W1T_HI; lo_off = W1T_LO; idx = j; }
  else if ((j -= 16384) < 4096){ int u = j >> 5, f = j & 31;
    v = V1[f*128 + u]; hi_off = V1T_HI; lo_off = V1T_LO; idx = j; }
  else if ((j -= 4096) < 40960){ int e = j / 10240, r = j % 10240, u = r / 160, k = r % 160;
    v = W2[e*10240 + k*64 + u]; hi_off = W2T_HI; lo_off = W2T_LO; idx = j; }
  else if ((j -= 40960) < 2048){ int u = j >> 5, f = j & 31;
    v = V2[f*64 + u]; hi_off = V2T_HI; lo_off = V2T_LO; idx = j; }
  else if ((j -= 2048) < 12288){ int ua = j / 96, k = j % 96;
    v = Wi[k*128 + ua]; hi_off = WIT_HI; lo_off = WIT_LO; idx = j; }
  else { j -= 12288; int ua = j / 96, k = j % 96;
    v = Wj[k*128 + ua]; hi_off = WJT_HI; lo_off = WJT_LO; idx = j; }
  f16 h = (f16)v;
  ws[hi_off + idx] = h;
  ws[lo_off + idx] = (f16)(v - (float)h);
}

// one block = one batch; 8 waves; edge-type split: waves 0..3 (eg=0) own
// e in {0,1}, waves 4..7 (eg=1) own e in {2,3}. 80 KB LDS -> 2 blocks/CU.
// Register model (rounds 2-5): per-EU budget 512 regs, arch/accum halves.
// (512,4) -> 64 arch + 64 agpr cap -> 16 waves/CU IF no spill; (512,2)
// relaxed to 92 arch + agpr > 128 total -> only 1 block resident (22% occ).
// This round: keep (512,4) and make the kernel FIT 64 arch: the former
// aggregation preloaded 48 arch regs of Wi/Wj fragments (the function-wide
// peak that forced rounds 2-4's scratch spill); now ks-outer streamed
// (16 transient), accumulating into iacc/jacc agprs.
__global__ __launch_bounds__(512, 4) void encoder_main(
    const float* __restrict__ adj, const float* __restrict__ node,
    const float* __restrict__ b1, const float* __restrict__ c1,
    const float* __restrict__ b2, const float* __restrict__ c2,
    const float* __restrict__ bi, const float* __restrict__ bj,
    const f16* __restrict__ wb, float* __restrict__ out)
{
  extern __shared__ unsigned char ldsb[];
  f16* adjh            = (f16*)(ldsb + ADJB_HI);
  unsigned char* adjl  = ldsb + ADJB_LO;
  f16* annh            = (f16*)(ldsb + ANNB_HI);
  unsigned char* annl  = ldsb + ANNB_LO;
  float* scr           = (float*)(ldsb + ANNB_HI);   // f32 merge scratch overlay
  f16* nodeH           = (f16*)(ldsb + PTB);          // staging overlay
  f16* nodeLo          = (f16*)(ldsb + PTB + 4096);   // staging overlay

  const int tid  = threadIdx.x;
  const int w    = tid >> 6;          // 0..7
  const int lane = tid & 63;
  const int q    = lane >> 4;
  const int l15  = lane & 15;
  const int eg   = w >> 2;            // edge group: e in {eg*2, eg*2+1}
  const int w4   = w & 3;             // u-slice index within group
  const int b    = blockIdx.x;
  const f32x4 z4 = {0.f, 0.f, 0.f, 0.f};

  // per-wave private transpose rows: 16 rows x 128 B hi + 16 rows x 64 B lo
  unsigned char* ptb = ldsb + ((w < 4) ? (PTB + w*2048) : (ANNB_HI + (w - 4)*2048));
  unsigned char* ptl = ldsb + ANNB_LO + w*1024;
  const int ptrow  = l15 * 128;
  const int ptlrow = l15 * 64;

  // ---------------- stage: adjacency + node -> split LDS ----------------
  {
    const float* ap = adj + (size_t)b * 20480;
    #pragma unroll
    for (int i = 0; i < 4; ++i){
      int fu = tid + 512*i;                       // fu = (e*64 + m)*8 + uc
      int e = fu >> 9, m = (fu >> 3) & 63, uc = fu & 7;
      const float* p = ap + (m*64 + uc*8)*5 + e + 1;    // skip edge type 0
      float v[8], lo[8]; f16x8 hi;
      #pragma unroll
      for (int jj = 0; jj < 8; ++jj) v[jj] = p[jj*5];
      #pragma unroll
      for (int jj = 0; jj < 8; ++jj){
        f16 h = (f16)v[jj]; hi[jj] = h; lo[jj] = v[jj] - (float)h;
      }
      int off = e*4096 + m*64 + ((uc ^ (m & 7)) * 8);
      *(f16x8*)&adjh[off] = hi;
      enc8(&adjl[off], lo);
    }
    if (tid < 256){
      const float* np = node + (size_t)b * 2048 + (tid & 63)*32 + (tid >> 6)*8;
      float4 a = *(const float4*)np, c = *(const float4*)(np + 4);
      float v[8] = {a.x, a.y, a.z, a.w, c.x, c.y, c.z, c.w};
      f16x8 hi, lo;
      #pragma unroll
      for (int jj = 0; jj < 8; ++jj){
        f16 h = (f16)v[jj]; hi[jj] = h; lo[jj] = (f16)(v[jj] - (float)h);
      }
      int n = tid & 63, un = tid >> 6;
      *(f16x8*)&nodeH [n*32 + ((un ^ (n & 3)) * 8)] = hi;
      *(f16x8*)&nodeLo[n*32 + ((un ^ (n & 3)) * 8)] = lo;
    }
  }
  __syncthreads();

  // node A-frags hi+lo (registers; node LDS region dead after this + barrier)
  f16x8 anh[4], anl[4];
  #pragma unroll
  for (int mt = 0; mt < 4; ++mt){
    anh[mt] = *(const f16x8*)&nodeH [(mt*16 + l15)*32 + ((q ^ (l15 & 3)) * 8)];
    anl[mt] = *(const f16x8*)&nodeLo[(mt*16 + l15)*32 + ((q ^ (l15 & 3)) * 8)];
  }
  __syncthreads();                                // protect PT/node overlay

  // ============ layer 1: h1 = tanh(sum_e A_e(node@W1+b1) + node@V1 + c1) ============
  f32x4 acc1[4][2];
  #pragma unroll
  for (int mt = 0; mt < 4; ++mt){ acc1[mt][0] = z4; acc1[mt][1] = z4; }

  #pragma unroll
  for (int i = 0; i < 2; ++i){
    const int e = eg*2 + i;
    #pragma unroll
    for (int ut = 0; ut < 2; ++ut){
      const int u = w4*32 + ut*16 + l15;
      f16x8 wh = *(const f16x8*)&wb[W1T_HI + (e*128 + u)*32 + q*8];
      f16x8 wl = *(const f16x8*)&wb[W1T_LO + (e*128 + u)*32 + q*8];
      float bias = b1[e*128 + u];
      #pragma unroll
      for (int mt = 0; mt < 4; ++mt){
        f32x4 pf = mfma16(anh[mt], wh, z4);
        pf = mfma16(anl[mt], wh, pf);
        pf = mfma16(anh[mt], wl, pf);
        f16x4 ph; float lo4[4];
        #pragma unroll
        for (int r = 0; r < 4; ++r){
          float v = pf[r] + bias;
          f16 h = (f16)v; ph[r] = h; lo4[r] = v - (float)h;
        }
        int unit = ((mt*2 + (q >> 1)) ^ (l15 & 7));      // n0 = mt*16+q*4
        *(f16x4*)(ptb + ptrow + unit*16 + (q & 1)*8) = ph;       // PT_HI[u_loc][n]
        *(u32*)(ptl + ptlrow + unit*8 + (q & 1)*4) = enc4(lo4);  // PT_LO
      }
      // adjacency fragments streamed per-(ks,mt): 8 regs transient, not 64.
      #pragma unroll
      for (int ks = 0; ks < 2; ++ks){
        int pu = ((ks*4 + q) ^ (l15 & 7));
        f16x8 bph = *(const f16x8*)(ptb + ptrow + pu*16);
        f16x8 bpl = dec8(ptl + ptlrow + pu*8);
        #pragma unroll
        for (int mt = 0; mt < 4; ++mt){
          int off = e*4096 + (mt*16 + l15)*64 + (((ks*4 + q) ^ (l15 & 7)) * 8);
          f16x8 ah = *(const f16x8*)&adjh[off];
          f16x8 al = dec8(&adjl[off]);
          acc1[mt][ut] = mfma16(ah, bph, acc1[mt][ut]);
          acc1[mt][ut] = mfma16(al, bph, acc1[mt][ut]);
          acc1[mt][ut] = mfma16(ah, bpl, acc1[mt][ut]);
        }
      }
    }
  }
  __syncthreads();   // B0: all PT/PT_LO reads done before scratch overlays them

  // merge: eg0 folds V1 term; eg1 publishes partials to f32 scratch.
  // scratch swizzle: u' = u ^ ((n&4)<<2) -> max 2-way bank alias (free).
  if (eg == 0){
    #pragma unroll
    for (int ut = 0; ut < 2; ++ut){
      const int u = w4*32 + ut*16 + l15;
      f16x8 wh = *(const f16x8*)&wb[V1T_HI + u*32 + q*8];
      f16x8 wl = *(const f16x8*)&wb[V1T_LO + u*32 + q*8];
      #pragma unroll
      for (int mt = 0; mt < 4; ++mt){
        acc1[mt][ut] = mfma16(anh[mt], wh, acc1[mt][ut]);
        acc1[mt][ut] = mfma16(anl[mt], wh, acc1[mt][ut]);
        acc1[mt][ut] = mfma16(anh[mt], wl, acc1[mt][ut]);
      }
    }
  } else {
    #pragma unroll
    for (int mt = 0; mt < 4; ++mt)
      #pragma unroll
      for (int ut = 0; ut < 2; ++ut)
        #pragma unroll
        for (int r = 0; r < 4; ++r){
          int n = mt*16 + q*4 + r;
          int u = w4*32 + ut*16 + l15;
          scr[n*128 + (u ^ ((n & 4) << 2))] = acc1[mt][ut][r];
        }
  }
  __syncthreads();   // B1: scratch ready
  if (eg == 0){
    #pragma unroll
    for (int mt = 0; mt < 4; ++mt)
      #pragma unroll
      for (int ut = 0; ut < 2; ++ut)
        #pragma unroll
        for (int r = 0; r < 4; ++r){
          int n = mt*16 + q*4 + r;
          int u = w4*32 + ut*16 + l15;
          acc1[mt][ut][r] += scr[n*128 + (u ^ ((n & 4) << 2))];
        }
  }
  __syncthreads();   // B2: scratch reads done before ann writes overlay it
  if (eg == 0){
    #pragma unroll
    for (int ut = 0; ut < 2; ++ut){
      const int u = w4*32 + ut*16 + l15;
      float cv = c1[u];
      #pragma unroll
      for (int mt = 0; mt < 4; ++mt)
        #pragma unroll
        for (int r = 0; r < 4; ++r){
          float h = fast_tanh(acc1[mt][ut][r] + cv);
          f16 hh = (f16)h;
          int row = mt*16 + q*4 + r;
          int unit = ((u >> 3) ^ (row & 7));
          annh[row*128 + unit*8 + (u & 7)] = hh;                   // h1 cols 0..127
          annl[row*128 + unit*8 + (u & 7)] = enc1(h - (float)hh);
        }
    }
  }
  __syncthreads();   // B3: h1 ready

  // ============ layer 2: h2 = tanh(sum_e A_e(ann@W2+b2) + node@V2 + c2) ============
  const int u2 = w4*16 + l15;
  f32x4 qf[2][4];                                 // [i][mt], group's 2 edge types
  #pragma unroll
  for (int mt = 0; mt < 4; ++mt){
    #pragma unroll
    for (int i = 0; i < 2; ++i){
      const int e = eg*2 + i;
      const f16* w2h = &wb[W2T_HI + (e*64 + u2)*160];
      const f16* w2l = &wb[W2T_LO + (e*64 + u2)*160];
      f16x8 wnh = *(const f16x8*)&w2h[4*32 + q*8];
      f16x8 wnl = *(const f16x8*)&w2l[4*32 + q*8];
      f32x4 t = mfma16(anh[mt], wnh, z4);          // node part k=128..159
      t = mfma16(anl[mt], wnh, t);
      t = mfma16(anh[mt], wnl, t);
      // ann fragments streamed per-(i,ks): 8 regs transient, not 64.
      #pragma unroll
      for (int ks = 0; ks < 4; ++ks){
        int off = (mt*16 + l15)*128 + (((ks*4 + q) ^ (l15 & 7)) * 8);
        f16x8 axh = *(const f16x8*)&annh[off];
        f16x8 axl = dec8(&annl[off]);
        f16x8 wh = *(const f16x8*)&w2h[ks*32 + q*8];
        f16x8 wl = *(const f16x8*)&w2l[ks*32 + q*8];
        t = mfma16(axh, wh, t);
        t = mfma16(axl, wh, t);
        t = mfma16(axh, wl, t);
      }
      qf[i][mt] = t;
    }
  }
  __syncthreads();   // B4: ann reads done before QT overlays annl / annh(eg1)

  f32x4 acc2[4];
  #pragma unroll
  for (int mt = 0; mt < 4; ++mt) acc2[mt] = z4;
  #pragma unroll
  for (int i = 0; i < 2; ++i){
    const int e = eg*2 + i;
    float bias = b2[e*64 + u2];
    #pragma unroll
    for (int mt = 0; mt < 4; ++mt){
      f16x4 ph; float lo4[4];
      #pragma unroll
      for (int r = 0; r < 4; ++r){
        float v = qf[i][mt][r] + bias;
        f16 h = (f16)v; ph[r] = h; lo4[r] = v - (float)h;
      }
      int unit = ((mt*2 + (q >> 1)) ^ (l15 & 7));
      *(f16x4*)(ptb + ptrow + unit*16 + (q & 1)*8) = ph;       // QT_HI[u_loc][n]
      *(u32*)(ptl + ptlrow + unit*8 + (q & 1)*4) = enc4(lo4);  // QT_LO
    }
    #pragma unroll
    for (int ks = 0; ks < 2; ++ks){
      int pu = ((ks*4 + q) ^ (l15 & 7));
      f16x8 bph = *(const f16x8*)(ptb + ptrow + pu*16);
      f16x8 bpl = dec8(ptl + ptlrow + pu*8);
      #pragma unroll
      for (int mt = 0; mt < 4; ++mt){
        int off = e*4096 + (mt*16 + l15)*64 + (((ks*4 + q) ^ (l15 & 7)) * 8);
        f16x8 ah = *(const f16x8*)&adjh[off];
        f16x8 al = dec8(&adjl[off]);
        acc2[mt] = mfma16(ah, bph, acc2[mt]);
        acc2[mt] = mfma16(al, bph, acc2[mt]);
        acc2[mt] = mfma16(ah, bpl, acc2[mt]);
      }
    }
  }
  // B4b: scr2 (16 KB @ ANNB_HI) overlays waves 4..7's QT_HI buffers — must
  // wait until ALL eg1 waves finish their QT reads, not just the writer.
  __syncthreads();
  if (eg == 0){
    f16x8 wh = *(const f16x8*)&wb[V2T_HI + u2*32 + q*8];
    f16x8 wl = *(const f16x8*)&wb[V2T_LO + u2*32 + q*8];
    #pragma unroll
    for (int mt = 0; mt < 4; ++mt){
      acc2[mt] = mfma16(anh[mt], wh, acc2[mt]);
      acc2[mt] = mfma16(anl[mt], wh, acc2[mt]);
      acc2[mt] = mfma16(anh[mt], wl, acc2[mt]);
    }
  } else {
    #pragma unroll
    for (int mt = 0; mt < 4; ++mt)
      #pragma unroll
      for (int r = 0; r < 4; ++r){
        int n = mt*16 + q*4 + r;
        scr[n*64 + (u2 ^ ((n & 4) << 2))] = acc2[mt][r];
      }
  }
  __syncthreads();   // B5: scratch2 ready
  if (eg == 0){
    #pragma unroll
    for (int mt = 0; mt < 4; ++mt)
      #pragma unroll
      for (int r = 0; r < 4; ++r){
        int n = mt*16 + q*4 + r;
        acc2[mt][r] += scr[n*64 + (u2 ^ ((n & 4) << 2))];
      }
  }
  __syncthreads();   // B6: scratch2 reads done before h2 writes overlay it
  if (eg == 0){
    float cv = c2[u2];
    const int uc = 64 + u2;
    #pragma unroll
    for (int mt = 0; mt < 4; ++mt)
      #pragma unroll
      for (int r = 0; r < 4; ++r){
        float h = fast_tanh(acc2[mt][r] + cv);
        f16 hh = (f16)h;
        int row = mt*16 + q*4 + r;
        int unit = ((uc >> 3) ^ (row & 7));
        annh[row*128 + unit*8 + (uc & 7)] = hh;                  // h2 cols 64..127
        annl[row*128 + unit*8 + (uc & 7)] = enc1(h - (float)hh);
      }
  }
  __syncthreads();   // B7: h2 ready

  // ============ aggregation: out = tanh(sum_n sigmoid(.)·tanh(.)) ============
  // ks-outer, weights streamed (16 transient arch regs instead of 48
  // persistent): accumulate i/j pre-activations in iacc/jacc agprs across
  // ks slices {h2 lo, h2 hi, node}; activation epilogue after.
  const int ua = w*16 + l15;                      // 8 waves x 16 = 128
  float bib = bi[ua], bjb = bj[ua];
  f32x4 iacc[4], jacc[4];
  #pragma unroll
  for (int mt = 0; mt < 4; ++mt){ iacc[mt] = z4; jacc[mt] = z4; }
  #pragma unroll
  for (int ks = 0; ks < 3; ++ks){
    f16x8 wih = *(const f16x8*)&wb[WIT_HI + ua*96 + ks*32 + q*8];
    f16x8 wil = *(const f16x8*)&wb[WIT_LO + ua*96 + ks*32 + q*8];
    f16x8 wjh = *(const f16x8*)&wb[WJT_HI + ua*96 + ks*32 + q*8];
    f16x8 wjl = *(const f16x8*)&wb[WJT_LO + ua*96 + ks*32 + q*8];
    if (ks < 2){
      #pragma unroll
      for (int mt = 0; mt < 4; ++mt){
        int off = (mt*16 + l15)*128 + (((8 + ks*4 + q) ^ (l15 & 7)) * 8);
        f16x8 gh = *(const f16x8*)&annh[off];
        f16x8 gl = dec8(&annl[off]);
        iacc[mt] = mfma16(gh, wih, iacc[mt]);
        iacc[mt] = mfma16(gl, wih, iacc[mt]);
        iacc[mt] = mfma16(gh, wil, iacc[mt]);
        jacc[mt] = mfma16(gh, wjh, jacc[mt]);
        jacc[mt] = mfma16(gl, wjh, jacc[mt]);
        jacc[mt] = mfma16(gh, wjl, jacc[mt]);
      }
    } else {
      #pragma unroll
      for (int mt = 0; mt < 4; ++mt){
        iacc[mt] = mfma16(anh[mt], wih, iacc[mt]);
        iacc[mt] = mfma16(anl[mt], wih, iacc[mt]);
        iacc[mt] = mfma16(anh[mt], wil, iacc[mt]);
        jacc[mt] = mfma16(anh[mt], wjh, jacc[mt]);
        jacc[mt] = mfma16(anl[mt], wjh, jacc[mt]);
        jacc[mt] = mfma16(anh[mt], wjl, jacc[mt]);
      }
    }
  }
  float s = 0.f;
  #pragma unroll
  for (int mt = 0; mt < 4; ++mt)
    #pragma unroll
    for (int r = 0; r < 4; ++r)
      s += fast_sigmoid(iacc[mt][r] + bib) * fast_tanh(jacc[mt][r] + bjb);
  s += __shfl_xor(s, 16);
  s += __shfl_xor(s, 32);
  if (q == 0) out[(size_t)b*128 + ua] = fast_tanh(s);
}

extern "C" void kernel_launch(void* const* d_in, const int* in_sizes, int n_in,
                              void* d_out, int out_size, void* d_ws, size_t ws_size,
                              hipStream_t stream) {
  (void)in_sizes; (void)n_in; (void)out_size; (void)ws_size;
  const float* adj  = (const float*)d_in[0];
  // d_in[1] = hidden (zeros, rank-2): unused by the reference path
  const float* node = (const float*)d_in[2];
  const float* W1   = (const float*)d_in[3];
  const float* b1   = (const float*)d_in[4];
  const float* V1   = (const float*)d_in[5];
  const float* c1   = (const float*)d_in[6];
  const float* W2   = (const float*)d_in[7];
  const float* b2   = (const float*)d_in[8];
  const float* V2   = (const float*)d_in[9];
  const float* c2   = (const float*)d_in[10];
  const float* Wi   = (const float*)d_in[11];
  const float* bi   = (const float*)d_in[12];
  const float* Wj   = (const float*)d_in[13];
  const float* bj   = (const float*)d_in[14];
  f16* wb    = (f16*)d_ws;
  float* out = (float*)d_out;

  hipFuncSetAttribute((const void*)encoder_main,
                      hipFuncAttributeMaxDynamicSharedMemorySize, LDS_BYTES);

  prep_weights<<<(WS_SRC + 255) / 256, 256, 0, stream>>>(W1, V1, W2, V2, Wi, Wj, wb);
  encoder_main<<<2048, 512, LDS_BYTES, stream>>>(adj, node, b1, c1, b2, c2, bi, bj, wb, out);
}